// Round 6
// baseline (969.808 us; speedup 1.0000x reference)
//
#include <hip/hip_runtime.h>
#include <math.h>

// CausalAttention: B=4, S=4096, DIN=DOUT=768, fp32 in/out, bf16 MFMA compute.
// ws layout: [0,256) unused | xb bf16 | q bf16 (pre-scaled) | k bf16 |
//            vT bf16 [b][d][s] | Wt bf16 (3x transposed W)

typedef unsigned short u16;
typedef unsigned int u32;
typedef __attribute__((ext_vector_type(8))) __bf16 bf8;
typedef __attribute__((ext_vector_type(4))) float f32x4;
typedef __attribute__((ext_vector_type(16))) float f32x16;

struct __align__(8) U4 { u16 x, y, z, w; };

#define LOG2E 1.4426950408889634f
#define QSCALE 0.03608439182435161f   // 1/sqrt(768)

#define SBAR() __builtin_amdgcn_s_barrier()
#define WAIT_LGKM0() asm volatile("s_waitcnt lgkmcnt(0)" ::: "memory")

__device__ __forceinline__ u16 f2bf(float f) {
  u32 u = __builtin_bit_cast(u32, f);
  u += 0x7FFFu + ((u >> 16) & 1u);      // RNE
  return (u16)(u >> 16);
}
__device__ __forceinline__ f32x4 mfma16(bf8 a, bf8 b, f32x4 c) {
  return __builtin_amdgcn_mfma_f32_16x16x32_bf16(a, b, c, 0, 0, 0);
}
__device__ __forceinline__ f32x16 mfma32(bf8 a, bf8 b, f32x16 c) {
  return __builtin_amdgcn_mfma_f32_32x32x16_bf16(a, b, c, 0, 0, 0);
}
__device__ __forceinline__ void stage16(const void* g, void* l) {
  __builtin_amdgcn_global_load_lds((const __attribute__((address_space(1))) void*)g,
                                   (__attribute__((address_space(3))) void*)l, 16, 0, 0);
}
// XOR swizzle for gemm (128B rows): key bits >=7 -> bits 4-6
__device__ __forceinline__ u32 swz7(u32 off) { return off ^ (((off >> 7) & 7u) << 4); }

// ---------------- convert x (fp32 -> bf16), vectorized ----------------
__global__ void cvt_x_kernel(const float* __restrict__ x, u16* __restrict__ xb) {
  int i = blockIdx.x * 256 + threadIdx.x;          // float4 index, exact grid
  float4 v = ((const float4*)x)[i];
  U4 o; o.x = f2bf(v.x); o.y = f2bf(v.y); o.z = f2bf(v.z); o.w = f2bf(v.w);
  ((U4*)xb)[i] = o;
}

// ---------------- convert + transpose W: Wt[z][n][k] = bf16(W_z[k][n]) ----------------
__global__ void cvt_w_kernel(const float* __restrict__ Wq, const float* __restrict__ Wk,
                             const float* __restrict__ Wv, u16* __restrict__ wt) {
  __shared__ float tile[32][33];
  int z = blockIdx.z;
  const float* W = (z == 0) ? Wq : ((z == 1) ? Wk : Wv);
  u16* o = wt + (size_t)z * 589824;
  int n0 = blockIdx.x * 32, k0 = blockIdx.y * 32;
  int c = threadIdx.x & 31, r0 = threadIdx.x >> 5;
#pragma unroll
  for (int p = 0; p < 4; p++) tile[r0 + p * 8][c] = W[(size_t)(k0 + r0 + p * 8) * 768 + n0 + c];
  __syncthreads();
#pragma unroll
  for (int p = 0; p < 4; p++) o[(size_t)(n0 + r0 + p * 8) * 768 + k0 + c] = f2bf(tile[c][r0 + p * 8]);
}

// ---------------- QKV GEMM: C[16384x768] = xb * W_z, 128x128 tile, BK=64 ----------------
__global__ __launch_bounds__(256) void gemm_qkv_kernel(
    const u16* __restrict__ xb, const u16* __restrict__ wt,
    u16* __restrict__ qo, u16* __restrict__ ko, u16* __restrict__ vT) {
  __shared__ char lA[16384];
  __shared__ char lB[16384];
  const int tid = threadIdx.x;
  const int lane = tid & 63, wvid = tid >> 6;
  const int wm = wvid >> 1, wn = wvid & 1;
  const int l15 = lane & 15, lg4 = lane >> 4;
  const int m0 = blockIdx.x * 128;
  const int n0 = blockIdx.y * 128;
  const int z = blockIdx.z;
  const u16* wz = wt + (size_t)z * 589824;

  f32x4 acc[4][4];
#pragma unroll
  for (int rt = 0; rt < 4; rt++)
#pragma unroll
    for (int nt = 0; nt < 4; nt++) acc[rt][nt] = f32x4{0.f, 0.f, 0.f, 0.f};

  for (int kt = 0; kt < 12; kt++) {
#pragma unroll
    for (int i = 0; i < 4; i++) {
      u32 o = (u32)i * 4096u + (u32)wvid * 1024u + (u32)lane * 16u;
      u32 lg = swz7(o);
      u32 row = lg >> 7, kbyt = lg & 127u;
      stage16((const char*)xb + ((size_t)(m0 + row) * 1536 + (size_t)kt * 128 + kbyt),
              lA + (size_t)i * 4096 + (size_t)wvid * 1024);
      stage16((const char*)wz + ((size_t)(n0 + row) * 1536 + (size_t)kt * 128 + kbyt),
              lB + (size_t)i * 4096 + (size_t)wvid * 1024);
    }
    __syncthreads();
#pragma unroll
    for (int kk = 0; kk < 2; kk++) {
      bf8 af[4], bfr[4];
#pragma unroll
      for (int rt = 0; rt < 4; rt++) {
        u32 off = (u32)(wm * 64 + rt * 16 + l15) * 128u + (u32)kk * 64u + (u32)lg4 * 16u;
        af[rt] = *(const bf8*)(const void*)(lA + swz7(off));
      }
#pragma unroll
      for (int nt = 0; nt < 4; nt++) {
        u32 off = (u32)(wn * 64 + nt * 16 + l15) * 128u + (u32)kk * 64u + (u32)lg4 * 16u;
        bfr[nt] = *(const bf8*)(const void*)(lB + swz7(off));
      }
#pragma unroll
      for (int rt = 0; rt < 4; rt++)
#pragma unroll
        for (int nt = 0; nt < 4; nt++) acc[rt][nt] = mfma16(af[rt], bfr[nt], acc[rt][nt]);
    }
    __syncthreads();
  }
  if (z == 2) {
#pragma unroll
    for (int rt = 0; rt < 4; rt++) {
      int m = m0 + wm * 64 + rt * 16 + lg4 * 4;
      int batch = m >> 12;
      int s = m & 4095;
#pragma unroll
      for (int nt = 0; nt < 4; nt++) {
        int col = n0 + wn * 64 + nt * 16 + l15;
        U4 pk;
        pk.x = f2bf(acc[rt][nt][0]); pk.y = f2bf(acc[rt][nt][1]);
        pk.z = f2bf(acc[rt][nt][2]); pk.w = f2bf(acc[rt][nt][3]);
        *(U4*)(vT + ((size_t)batch * 768 + col) * 4096 + s) = pk;
      }
    }
  } else {
    u16* dst = (z == 0) ? qo : ko;
    float scl = (z == 0) ? QSCALE : 1.0f;
#pragma unroll
    for (int rt = 0; rt < 4; rt++)
#pragma unroll
      for (int nt = 0; nt < 4; nt++) {
        int col = n0 + wn * 64 + nt * 16 + l15;
#pragma unroll
        for (int j = 0; j < 4; j++) {
          int m = m0 + wm * 64 + rt * 16 + lg4 * 4 + j;
          dst[(size_t)m * 768 + col] = f2bf(acc[rt][nt][j] * scl);
        }
      }
  }
}

// ---------------- flash attention v6: swapped-QK mfma32, no K/Q staging ----------------
// 8 waves, BQ=32, KBLK=256. Wave wv owns key-subtile [kb+wv*32, +32) for QK and
// output cols [wv*96, +96) for PV. S^T = mfma32(A=K, B=Q): lane&31 = q-row,
// regs = keys -> softmax is lane-local (15 fmax + shfl_xor(32)). Cross-wave
// merge via tiny LDS (pm8/ps8), all-lane. P packed bf16 via v_cvt_pk into
// P_lds[32 rows][256 keys] (XOR-swizzled 16B blocks). PV: A=P from LDS,
// B=V direct from global (vT [b][d][s]). No global_load_lds, 3 barriers/kt.
__global__ __launch_bounds__(512, 4) void attn_kernel(
    const u16* __restrict__ qg, const u16* __restrict__ kg, const u16* __restrict__ vg,
    float* __restrict__ out) {
  __shared__ char Pl[16384];
  __shared__ float pm8[8][32];
  __shared__ float ps8[8][32];
  __shared__ float alpha_sm[32];
  __shared__ float lsum_sm[32];

  const int tid = threadIdx.x;
  const int lane = tid & 63;
  const int wv = tid >> 6;           // 0..7
  const int l31 = lane & 31;
  const int hi = lane >> 5;          // 0..1

  const int b = blockIdx.x;
  const int qb_i = 127 - (b >> 2);   // biggest first (LPT backfill balances)
  const int batch = b & 3;
  const int qbase = qb_i * 32;
  const size_t boff = (size_t)batch * 4096;
  const int ntile = (qbase + 32 + 255) >> 8;

  const u16* qP = qg + (boff + qbase + l31) * 768 + hi * 8;
  const u16* kB = kg + boff * 768 + (size_t)(wv * 32 + l31) * 768 + hi * 8;
  const u16* vP = vg + ((size_t)batch * 768 + wv * 96 + l31) * 4096 + hi * 8;
  const u32 pswz = (u32)(l31 & 7) << 4;

  float mrow = -INFINITY, lrow = 0.f;
  f32x16 o0, o1, o2;
#pragma unroll
  for (int r = 0; r < 16; r++) { o0[r] = 0.f; o1[r] = 0.f; o2[r] = 0.f; }

  for (int kt = 0; kt < ntile; kt++) {
    const int kb = kt * 256;
    // ---- QK^T (swapped): S^T[32 keys x 32 rows], D-reduction in regs ----
    f32x16 s;
#pragma unroll
    for (int r = 0; r < 16; r++) s[r] = 0.f;
    {
      const u16* kP = kB + (size_t)kb * 768;
#pragma unroll 4
      for (int sl = 0; sl < 48; ++sl) {
        bf8 kf = *(const bf8*)(const void*)(kP + sl * 16);
        bf8 qf = *(const bf8*)(const void*)(qP + sl * 16);
        s = mfma32(kf, qf, s);
      }
    }
    // ---- causal mask (last tile only; fully-masked waves yield p=0) ----
    if (kt == ntile - 1) {
      const int rowg = qbase + l31;
#pragma unroll
      for (int r = 0; r < 16; r++) {
        int keyg = kb + wv * 32 + (r & 3) + 8 * (r >> 2) + 4 * hi;
        if (keyg > rowg) s[r] = -INFINITY;
      }
    }
    // ---- lane-local row max over this wave's 32 keys ----
    float tmax;
    {
      float a0 = fmaxf(fmaxf(s[0], s[1]), fmaxf(s[2], s[3]));
      float a1 = fmaxf(fmaxf(s[4], s[5]), fmaxf(s[6], s[7]));
      float a2 = fmaxf(fmaxf(s[8], s[9]), fmaxf(s[10], s[11]));
      float a3 = fmaxf(fmaxf(s[12], s[13]), fmaxf(s[14], s[15]));
      tmax = fmaxf(fmaxf(a0, a1), fmaxf(a2, a3));
      tmax = fmaxf(tmax, __shfl_xor(tmax, 32));
    }
    if (hi == 0) pm8[wv][l31] = tmax;
    WAIT_LGKM0(); SBAR();                      // B1: pm visible
    // ---- global tile max, alpha (all lanes, per q-row = l31) ----
    float tilemax = pm8[0][l31];
#pragma unroll
    for (int w = 1; w < 8; w++) tilemax = fmaxf(tilemax, pm8[w][l31]);
    const float mnew = fmaxf(mrow, tilemax);
    const float al = exp2f((mrow - mnew) * LOG2E);
    mrow = mnew;
    // ---- p = exp(s-m), lane-local sum, pack to P_lds ----
    float psum = 0.f;
    float p[16];
#pragma unroll
    for (int r = 0; r < 16; r++) { p[r] = exp2f((s[r] - mnew) * LOG2E); psum += p[r]; }
    psum += __shfl_xor(psum, 32);
    if (hi == 0) { ps8[wv][l31] = psum; if (wv == 0) alpha_sm[l31] = al; }
#pragma unroll
    for (int i = 0; i < 8; i++) {
      u32 pk;
      asm("v_cvt_pk_bf16_f32 %0, %1, %2" : "=v"(pk) : "v"(p[2 * i]), "v"(p[2 * i + 1]));
      u32 k0 = (u32)(wv * 32) + (u32)((2 * i) & 3) + 8u * (u32)(i >> 1) + 4u * (u32)hi;
      u32 ad = ((u32)l31 * 512u + k0 * 2u) ^ pswz;
      *(u32*)(void*)(Pl + ad) = pk;
    }
    WAIT_LGKM0(); SBAR();                      // B2: ps, alpha, P visible
    // ---- l update + O rescale ----
    {
      float lt = ps8[0][l31];
#pragma unroll
      for (int w = 1; w < 8; w++) lt += ps8[w][l31];
      lrow = lrow * al + lt;
    }
#pragma unroll
    for (int r = 0; r < 16; r++) {
      float av = alpha_sm[(r & 3) + 8 * (r >> 2) + 4 * hi];
      o0[r] *= av; o1[r] *= av; o2[r] *= av;
    }
    // ---- PV: O[32 rows x 96 cols] += P[32x256] * V[256x96] ----
    {
      const u16* vk = vP + kb;
#pragma unroll 4
      for (int ks = 0; ks < 16; ++ks) {
        u32 aad = (u32)l31 * 512u + ((((u32)ks * 32u) + (u32)hi * 16u) ^ pswz);
        bf8 pa = *(const bf8*)(const void*)(Pl + aad);
        bf8 v0 = *(const bf8*)(const void*)(vk + ks * 16);
        bf8 v1 = *(const bf8*)(const void*)(vk + 131072 + ks * 16);
        bf8 v2 = *(const bf8*)(const void*)(vk + 262144 + ks * 16);
        o0 = mfma32(pa, v0, o0);
        o1 = mfma32(pa, v1, o1);
        o2 = mfma32(pa, v2, o2);
      }
    }
    WAIT_LGKM0(); SBAR();                      // B3: P_lds reads done before next kt
  }
  // ---- epilogue: normalize and store fp32 ----
  if (hi == 0 && wv == 0) lsum_sm[l31] = lrow;
  WAIT_LGKM0(); SBAR();
#pragma unroll
  for (int r = 0; r < 16; r++) {
    const int row = (r & 3) + 8 * (r >> 2) + 4 * hi;
    const float inv = 1.f / lsum_sm[row];
    size_t o = (boff + (size_t)(qbase + row)) * 768 + wv * 96 + l31;
    out[o] = o0[r] * inv;
    out[o + 32] = o1[r] * inv;
    out[o + 64] = o2[r] * inv;
  }
}

extern "C" void kernel_launch(void* const* d_in, const int* in_sizes, int n_in,
                              void* d_out, int out_size, void* d_ws, size_t ws_size,
                              hipStream_t stream) {
  const float* x  = (const float*)d_in[0];
  const float* Wq = (const float*)d_in[1];
  const float* Wk = (const float*)d_in[2];
  const float* Wv = (const float*)d_in[3];
  float* out = (float*)d_out;

  char* ws = (char*)d_ws;
  u16* xb = (u16*)(ws + 256);
  u16* qb = xb + 12582912;
  u16* kb = qb + 12582912;
  u16* vT = kb + 12582912;
  u16* wt = vT + 12582912;     // 3 x 589824

  cvt_x_kernel<<<12288, 256, 0, stream>>>(x, xb);
  cvt_w_kernel<<<dim3(24, 24, 3), 256, 0, stream>>>(Wq, Wk, Wv, wt);
  gemm_qkv_kernel<<<dim3(128, 6, 3), 256, 0, stream>>>(xb, wt, qb, kb, vT);
  attn_kernel<<<512, 512, 0, stream>>>(qb, kb, vT, out);
}